// Round 11
// baseline (1151.865 us; speedup 1.0000x reference)
//
#include <hip/hip_runtime.h>
#include <hip/hip_bf16.h>
#include <stdint.h>

#define NB 4
#define CQ 512
#define CK 256
#define TT 4096
#define NCH 2
#define SCH (TT / NCH)
#define SCALE_QK 0.21022410381342863f  // 512^-0.25
#define LOG2E 1.44269504088896f
#define THR2 11.5416f                  // defer-max threshold 8 in log2 domain

using bf16x8 = __attribute__((ext_vector_type(8))) short;
using f32x4  = __attribute__((ext_vector_type(4))) float;
using u32x4  = __attribute__((ext_vector_type(4))) unsigned int;
typedef unsigned short u16;

__device__ __forceinline__ u16 f2bf(float f) {
    union { float f; unsigned u; } v; v.f = f;
    return (u16)((v.u + 0x7fffu + ((v.u >> 16) & 1u)) >> 16);
}
__device__ __forceinline__ float bf2f(u16 h) {
    union { float f; unsigned u; } v; v.u = ((unsigned)h) << 16;
    return v.f;
}
__device__ __forceinline__ bf16x8 pack8(f32x4 a, f32x4 b) {
    bf16x8 r;
    r[0] = (short)f2bf(a[0]); r[1] = (short)f2bf(a[1]);
    r[2] = (short)f2bf(a[2]); r[3] = (short)f2bf(a[3]);
    r[4] = (short)f2bf(b[0]); r[5] = (short)f2bf(b[1]);
    r[6] = (short)f2bf(b[2]); r[7] = (short)f2bf(b[3]);
    return r;
}
// async global->LDS, 16B per lane; LDS dest = wave-uniform base + lane*16
__device__ __forceinline__ void gload_lds16(const void* g, void* l) {
    __builtin_amdgcn_global_load_lds(
        (const __attribute__((address_space(1))) unsigned int*)g,
        (__attribute__((address_space(3))) unsigned int*)l, 16, 0, 0);
}

// ---- weight f32 -> bf16 conversion; [0,s1): *SCALE_QK*LOG2E, [s1,s2): *SCALE_QK ----
__global__ __launch_bounds__(256) void wconv_kernel(const float* __restrict__ src,
        u16* __restrict__ dst, int n, int s1, int s2) {
    int i = (blockIdx.x * 256 + threadIdx.x) * 8;
    if (i >= n) return;
    f32x4 a = *(const f32x4*)(src + i);
    f32x4 c = *(const f32x4*)(src + i + 4);
    float sc = (i < s1) ? SCALE_QK * LOG2E : ((i < s2) ? SCALE_QK : 1.f);
    a *= sc;
    c *= sc;
    *(bf16x8*)(dst + i) = pack8(a, c);
}

// ---- 2x2 avg pool of key_feat (b,256,128,128) -> kdsT (b,4096,256) bf16 ----
__global__ __launch_bounds__(256) void pool_tr_kernel(const float* __restrict__ kf,
                                                      u16* __restrict__ kdsT) {
    int h = blockIdx.x, b = blockIdx.y;
    __shared__ u16 tile[64][264];  // [w][c], padded
    for (int idx = threadIdx.x; idx < 64 * 256; idx += 256) {
        int w = idx & 63, c = idx >> 6;
        const float* base = kf + (((size_t)b * CK + c) * 128 + 2 * h) * 128 + 2 * w;
        float2 r0 = *(const float2*)base;
        float2 r1 = *(const float2*)(base + 128);
        tile[w][c] = f2bf(0.25f * (r0.x + r0.y + r1.x + r1.y));
    }
    __syncthreads();
    for (int idx = threadIdx.x; idx < 64 * 32; idx += 256) {
        int w = idx >> 5, cg = (idx & 31) << 3;
        *(u32x4*)(kdsT + ((size_t)b * TT + h * 64 + w) * CK + cg) = *(const u32x4*)&tile[w][cg];
    }
}

// ---- GroupNorm stats -> per-channel scale/shift (folded affine) ----
template <int ISBF>
__global__ __launch_bounds__(256) void gn_stats_kernel(const void* __restrict__ xv,
        const float* __restrict__ gw, const float* __restrict__ gb,
        float* __restrict__ sc, float* __restrict__ sh) {
    int g = blockIdx.x, b = blockIdx.y;
    size_t base = ((size_t)b * CQ + g * 16) * TT;
    float s = 0.f, q = 0.f;
    for (int i = threadIdx.x * 4; i < 16 * TT; i += 256 * 4) {
        float v0, v1, v2, v3;
        if constexpr (ISBF) {
            const u16* x = (const u16*)xv;
            uint2 u = *(const uint2*)(x + base + i);
            v0 = bf2f((u16)(u.x & 0xffff)); v1 = bf2f((u16)(u.x >> 16));
            v2 = bf2f((u16)(u.y & 0xffff)); v3 = bf2f((u16)(u.y >> 16));
        } else {
            const float* x = (const float*)xv;
            f32x4 v = *(const f32x4*)(x + base + i);
            v0 = v[0]; v1 = v[1]; v2 = v[2]; v3 = v[3];
        }
        s += v0 + v1 + v2 + v3;
        q += v0 * v0 + v1 * v1 + v2 * v2 + v3 * v3;
    }
#pragma unroll
    for (int d = 1; d < 64; d <<= 1) { s += __shfl_xor(s, d, 64); q += __shfl_xor(q, d, 64); }
    __shared__ float shs[4], shq[4];
    int wid = threadIdx.x >> 6;
    if ((threadIdx.x & 63) == 0) { shs[wid] = s; shq[wid] = q; }
    __syncthreads();
    if (threadIdx.x < 16) {
        float S = shs[0] + shs[1] + shs[2] + shs[3];
        float Q = shq[0] + shq[1] + shq[2] + shq[3];
        const float inv = 1.f / (16.f * TT);
        float mean = S * inv, var = Q * inv - mean * mean;
        float rstd = rsqrtf(var + 1e-5f);
        int c = g * 16 + threadIdx.x;
        float w = gw[c] * rstd;
        sc[b * CQ + c] = w;
        sh[b * CQ + c] = gb[c] - mean * w;
    }
}

// ---- affine + transpose: in (b,512,T) -> out (b,T,512) bf16 ----
template <int ISBF>
__global__ __launch_bounds__(256) void affine_tr_kernel(const void* __restrict__ xv,
        const float* __restrict__ sc, const float* __restrict__ sh, u16* __restrict__ out) {
    int t0 = blockIdx.x * 64, c0 = blockIdx.y * 64, b = blockIdx.z;
    __shared__ u16 tile[64][72];  // [t][c]
    for (int idx = threadIdx.x; idx < 64 * 64; idx += 256) {
        int tl = idx & 63, cl = idx >> 6;
        int c = c0 + cl;
        float v;
        if constexpr (ISBF) v = bf2f(((const u16*)xv)[((size_t)b * CQ + c) * TT + t0 + tl]);
        else                v = ((const float*)xv)[((size_t)b * CQ + c) * TT + t0 + tl];
        tile[tl][cl] = f2bf(v * sc[b * CQ + c] + sh[b * CQ + c]);
    }
    __syncthreads();
    for (int idx = threadIdx.x; idx < 64 * 8; idx += 256) {
        int tl = idx >> 3, cg = (idx & 7) << 3;
        *(u32x4*)(out + ((size_t)b * TT + t0 + tl) * CQ + c0 + cg) = *(const u32x4*)&tile[tl][cg];
    }
}

// ---- staged GEMM: 128o x 128t tile, BK=64, double-buffered LDS, global_load_lds ----
template <int EPI, int CONCAT, int SWAP>
__global__ __launch_bounds__(256) void gemm_st_kernel(
        const u16* __restrict__ Wb, const u16* __restrict__ X1, const u16* __restrict__ X2,
        int Ktot, const float* __restrict__ bias,
        u16* __restrict__ outb, u16* __restrict__ outb2, float* __restrict__ outf,
        const float* __restrict__ query, const float* __restrict__ qsc,
        const float* __restrict__ qsh) {
    int b = blockIdx.z;
    int o0 = blockIdx.x * 128, t0 = blockIdx.y * 128;
    int wid = threadIdx.x >> 6, lane = threadIdx.x & 63;
    int lr = lane & 15, lg = lane >> 4;
    int osub = (wid >> 1) * 64, tsub = (wid & 1) * 64;

    __shared__ u16 Wl[2][128][64];
    __shared__ u16 Xl[2][128][64];

    const int Kx = CONCAT ? 512 : Ktot;
    int srow = lane >> 3;
    int sxw = ((lane & 7) ^ srow) << 4;
    int xr = (lr & 7) << 4;

    f32x4 acc[4][4];
#pragma unroll
    for (int i = 0; i < 4; i++)
#pragma unroll
        for (int j = 0; j < 4; j++) acc[i][j] = f32x4{0.f, 0.f, 0.f, 0.f};

    int nk = Ktot >> 6;

#define STAGE_TILE(KC, BUF)                                                          \
    do {                                                                             \
        int c0_ = (KC) << 6;                                                         \
        const u16* xs_;                                                              \
        if (CONCAT && c0_ >= 512) xs_ = X2 + ((size_t)b * TT) * 512 + (c0_ - 512);   \
        else if (CONCAT)          xs_ = X1 + ((size_t)b * TT) * 512 + c0_;           \
        else                      xs_ = X1 + ((size_t)b * TT) * (size_t)Ktot + c0_;  \
        const char* xb_ = (const char*)(xs_ + (size_t)(t0 + wid * 32) * Kx) + sxw;   \
        const char* wb_ = (const char*)(Wb + (size_t)(o0 + wid * 32) * Ktot + c0_) + sxw; \
        _Pragma("unroll")                                                            \
        for (int i_ = 0; i_ < 4; i_++) {                                             \
            gload_lds16(xb_ + (size_t)(i_ * 8 + srow) * (Kx * 2),                    \
                        &Xl[BUF][wid * 32 + i_ * 8][0]);                             \
            gload_lds16(wb_ + (size_t)(i_ * 8 + srow) * (Ktot * 2),                  \
                        &Wl[BUF][wid * 32 + i_ * 8][0]);                             \
        }                                                                            \
    } while (0)

    STAGE_TILE(0, 0);
    __syncthreads();
    int cur = 0;
    for (int kc = 0; kc < nk; kc++) {
        if (kc + 1 < nk) STAGE_TILE(kc + 1, cur ^ 1);
#pragma unroll
        for (int kk = 0; kk < 2; kk++) {
            int boff = (kk * 64 + lg * 16) ^ xr;
            bf16x8 am[4], bn[4];
#pragma unroll
            for (int mi = 0; mi < 4; mi++) {
                if (SWAP) am[mi] = *(const bf16x8*)((const char*)&Xl[cur][tsub + mi * 16 + lr][0] + boff);
                else      am[mi] = *(const bf16x8*)((const char*)&Wl[cur][osub + mi * 16 + lr][0] + boff);
            }
#pragma unroll
            for (int ni = 0; ni < 4; ni++) {
                if (SWAP) bn[ni] = *(const bf16x8*)((const char*)&Wl[cur][osub + ni * 16 + lr][0] + boff);
                else      bn[ni] = *(const bf16x8*)((const char*)&Xl[cur][tsub + ni * 16 + lr][0] + boff);
            }
#pragma unroll
            for (int mi = 0; mi < 4; mi++)
#pragma unroll
                for (int ni = 0; ni < 4; ni++)
                    acc[mi][ni] = __builtin_amdgcn_mfma_f32_16x16x32_bf16(am[mi], bn[ni], acc[mi][ni], 0, 0, 0);
        }
        __syncthreads();
        cur ^= 1;
    }
#undef STAGE_TILE

    if (SWAP) {
#pragma unroll
        for (int mi = 0; mi < 4; mi++)
#pragma unroll
            for (int ni = 0; ni < 4; ni++)
#pragma unroll
                for (int reg = 0; reg < 4; reg++) {
                    int t = t0 + tsub + mi * 16 + 4 * lg + reg;
                    int o = o0 + osub + ni * 16 + lr;
                    float bscale = (o < 512) ? SCALE_QK * LOG2E : SCALE_QK;
                    float v = acc[mi][ni][reg] + bias[o] * bscale;
                    if (o < 512) outb[((size_t)b * TT + t) * 512 + o] = f2bf(v);
                    else         outb2[((size_t)b * TT + t) * 512 + (o - 512)] = f2bf(v);
                }
    } else {
#pragma unroll
        for (int mi = 0; mi < 4; mi++)
#pragma unroll
            for (int reg = 0; reg < 4; reg++) {
                int o = o0 + osub + mi * 16 + 4 * lg + reg;
                float bv = (EPI >= 1) ? bias[o] : 0.f;
#pragma unroll
                for (int ni = 0; ni < 4; ni++) {
                    int t = t0 + tsub + ni * 16 + lr;
                    size_t oidx = ((size_t)b * CQ + o) * TT + t;
                    float v = acc[mi][ni][reg] + bv;
                    if (EPI == 2) {
                        outf[oidx] = v + query[oidx] * qsc[b * CQ + o] + qsh[b * CQ + o];
                    } else {
                        outb[oidx] = f2bf(v);
                    }
                }
            }
    }
}

// ---- flash attention v11: R8 geometry (s32, NCH=2, 2 blocks/CU) with register diet.
// Q streamed from global per k-step (no Q registers); m double-buffered in LDS;
// l maintained in LDS by wave 0; branchless fac; log2-domain softmax (exp2).
// QK role: (tb 0..3, sb 0..1) -> 16t x 16s. PV role: (tb2 0..1, sbq 0..3) -> 32t x 128c.
__global__ __launch_bounds__(512, 4) void flash_kernel(
        const u16* __restrict__ qqT, const u16* __restrict__ kkT,
        const u16* __restrict__ vv, const float* __restrict__ WM,
        u16* __restrict__ pacc, float* __restrict__ pm, float* __restrict__ pl) {
    int b = blockIdx.z, ch = blockIdx.y;
    int T0 = blockIdx.x * 64;
    int wid = threadIdx.x >> 6, lane = threadIdx.x & 63;
    int lr = lane & 15, lg = lane >> 4;
    int tb = wid >> 1, sb = wid & 1;      // QK roles
    int tb2 = wid >> 2, sbq = wid & 3;    // PV roles

    __shared__ u16 K_lds[32][512];   // 32KB, 16B-chunk swizzled by (s&7)
    __shared__ u16 V_lds[512][32];   // 32KB, chunk swizzled by ((c>>1)&3)
    __shared__ u16 p_lds[64][32];    // 4KB, chunk swizzled by ((t>>1)&3)
    __shared__ float exv[64][4];     // {max0, sum0, max1, sum1} per t
    __shared__ float m_dbuf[2][64];  // running max (log2), double-buffered
    __shared__ float l_lds[64];      // running denom, wave0-maintained

    if (threadIdx.x < 64) {
        m_dbuf[0][threadIdx.x] = 0.f;
        l_lds[threadIdx.x] = 0.f;
    }

    f32x4 acc[2][8];
#pragma unroll
    for (int i = 0; i < 2; i++)
#pragma unroll
        for (int j = 0; j < 8; j++) acc[i][j] = f32x4{0.f, 0.f, 0.f, 0.f};

    const float* wmrow = WM + ((size_t)b * TT + T0 + 16 * tb + 4 * lg) * TT + 16 * sb + lr;
    const char* kbase = (const char*)(kkT + (size_t)b * TT * CQ);
    const char* vbase = (const char*)(vv + (size_t)b * CQ * TT);
    const u16* qrow = qqT + ((size_t)b * TT + T0 + 16 * tb + lr) * CQ;
    int myt = 16 * tb + 4 * lg;
    int sbeg = ch * SCH;

#pragma unroll 1
    for (int it = 0; it < SCH / 32; it++) {
        int s0 = sbeg + it * 32;
        int cur = it & 1;
        // bar1: prev tile consumed; LDS state (m/l/exv) from prev iter visible
        asm volatile("s_waitcnt lgkmcnt(0)\ns_barrier" ::: "memory");
        // stage K (4 rows of 1KB per wave) + V (4 groups) : 8 async gloads
#pragma unroll
        for (int i = 0; i < 4; i++) {
            int s = 4 * wid + i;
            gload_lds16(kbase + (size_t)(s0 + s) * 1024 + ((lane ^ (s & 7)) << 4),
                        &K_lds[s][0]);
        }
#pragma unroll
        for (int g = 0; g < 4; g++) {
            int c0 = 64 * wid + 16 * g;
            int c = c0 + (lane >> 2);
            gload_lds16(vbase + (size_t)c * (TT * 2) + (size_t)s0 * 2 +
                            ((((lane & 3) ^ ((c >> 1) & 3))) << 4),
                        &V_lds[c0][0]);
        }
        __builtin_amdgcn_sched_barrier(0);
        // WM scalar loads (4) stay in flight past bar2
        float wmv[4];
#pragma unroll
        for (int r = 0; r < 4; r++) wmv[r] = wmrow[(size_t)r * TT + s0];
        // running max for this wave's QK rows (b128)
        f32x4 mqv = *(const f32x4*)&m_dbuf[cur][myt];
        __builtin_amdgcn_sched_barrier(0);
        // bar2: drain the 8 K/V gloads block-wide; WM loads remain outstanding
        asm volatile("s_waitcnt vmcnt(4) lgkmcnt(0)\ns_barrier" ::: "memory");

        // QK: S[16t x 16s]; Q streamed from global (L2/L3-resident, same addrs each iter)
        f32x4 sacc = f32x4{0.f, 0.f, 0.f, 0.f};
        {
            int srow = 16 * sb + lr;
            const char* kp = (const char*)&K_lds[srow][0];
            int sw = srow & 7;
#pragma unroll 2
            for (int kc = 0; kc < 16; kc++) {
                bf16x8 qf = *(const bf16x8*)(qrow + kc * 32 + lg * 8);
                bf16x8 kfr = *(const bf16x8*)(kp + ((((kc << 2) | lg) ^ sw) << 4));
                sacc = __builtin_amdgcn_mfma_f32_16x16x32_bf16(qf, kfr, sacc, 0, 0, 0);
            }
        }
        // logits (log2 domain); P = exp2(lgt - m_old); partial max+sum over 16 s
        float pmax[4], psum[4];
#pragma unroll
        for (int reg = 0; reg < 4; reg++) {
            float v = sacc[reg] * wmv[reg];
            pmax[reg] = v;
            float p = exp2f(v - mqv[reg]);
            psum[reg] = p;
            int t = myt + reg;
            int s = 16 * sb + lr;
            *(u16*)((char*)p_lds + t * 64 + ((((s >> 3) ^ ((t >> 1) & 3))) << 4) + ((s & 7) << 1)) = f2bf(p);
        }
#pragma unroll
        for (int d = 1; d < 16; d <<= 1)
#pragma unroll
            for (int reg = 0; reg < 4; reg++) {
                pmax[reg] = fmaxf(pmax[reg], __shfl_xor(pmax[reg], d, 64));
                psum[reg] += __shfl_xor(psum[reg], d, 64);
            }
        if (lr == 0) {
#pragma unroll
            for (int reg = 0; reg < 4; reg++) {
                float2 e; e.x = pmax[reg]; e.y = psum[reg];
                *(float2*)((char*)exv + (myt + reg) * 16 + sb * 8) = e;
            }
        }
        // bar3: P + stats visible block-wide
        asm volatile("s_waitcnt lgkmcnt(0)\ns_barrier" ::: "memory");

        // PV: acc[32t x 128c] += P[32t x 32s] * V[128c x 32s]
        {
            bf16x8 pa[2];
#pragma unroll
            for (int mi = 0; mi < 2; mi++) {
                int prow = 32 * tb2 + mi * 16 + lr;
                pa[mi] = *(const bf16x8*)((const char*)p_lds + prow * 64 +
                                          ((lg ^ ((prow >> 1) & 3)) << 4));
            }
#pragma unroll
            for (int nc = 0; nc < 8; nc++) {
                int vr = 128 * sbq + nc * 16 + lr;
                bf16x8 vf = *(const bf16x8*)((const char*)V_lds + vr * 64 +
                                             ((lg ^ ((vr >> 1) & 3)) << 4));
#pragma unroll
                for (int mi = 0; mi < 2; mi++)
                    acc[mi][nc] = __builtin_amdgcn_mfma_f32_16x16x32_bf16(pa[mi], vf, acc[mi][nc], 0, 0, 0);
            }
        }
        // branchless rescale from shared state (fac == 1 when deferred)
#pragma unroll
        for (int mi = 0; mi < 2; mi++) {
            int tba = 32 * tb2 + mi * 16 + 4 * lg;
            f32x4 mo = *(const f32x4*)&m_dbuf[cur][tba];
#pragma unroll
            for (int reg = 0; reg < 4; reg++) {
                f32x4 e = *(const f32x4*)&exv[tba + reg][0];
                float pmx = fmaxf(e[0], e[2]);
                float mn = (pmx > mo[reg] + THR2) ? pmx : mo[reg];
                float fac = exp2f(mo[reg] - mn);
#pragma unroll
                for (int nc = 0; nc < 8; nc++) acc[mi][nc][reg] *= fac;
            }
        }
        // wave 0: update shared m (next buffer) and l
        if (wid == 0) {
            int t = lane;
            f32x4 e = *(const f32x4*)&exv[t][0];
            float mo = m_dbuf[cur][t];
            float pmx = fmaxf(e[0], e[2]);
            float sum = e[1] + e[3];
            float mn = (pmx > mo + THR2) ? pmx : mo;
            float fac = exp2f(mo - mn);
            l_lds[t] = l_lds[t] * fac + sum;
            m_dbuf[cur ^ 1][t] = mn;
        }
    }
    __syncthreads();
    // epilogue: per-chunk normalize + store partials
    int mbuf = (SCH / 32) & 1;
    size_t row = (size_t)(ch * NB + b) * TT;
#pragma unroll
    for (int mi = 0; mi < 2; mi++) {
        int tba = 32 * tb2 + mi * 16 + 4 * lg;
#pragma unroll
        for (int reg = 0; reg < 4; reg++) {
            float inv = 1.f / l_lds[tba + reg];
#pragma unroll
            for (int nc = 0; nc < 8; nc++) {
                int t = T0 + tba + reg;
                int c = 128 * sbq + nc * 16 + lr;
                pacc[(row + t) * CQ + c] = f2bf(acc[mi][nc][reg] * inv);
            }
        }
    }
    if (threadIdx.x < 64) {
        int t = threadIdx.x;
        pm[row + T0 + t] = m_dbuf[mbuf][t];
        pl[row + T0 + t] = l_lds[t];
    }
}

// ---- combine split-KV partials: aT[b][t][c] = sum_ch w_ch * pacc_ch (log2-domain m) ----
__global__ __launch_bounds__(256) void combine_kernel(
        const u16* __restrict__ pacc, const float* __restrict__ pm,
        const float* __restrict__ pl, u16* __restrict__ aT) {
    int b = blockIdx.y;
    int t = blockIdx.x * 4 + (threadIdx.x >> 6);
    int cg = (threadIdx.x & 63) * 8;
    size_t r0 = (size_t)(0 * NB + b) * TT + t;
    size_t r1 = (size_t)(1 * NB + b) * TT + t;
    float m0 = pm[r0], m1 = pm[r1];
    float l0 = pl[r0], l1 = pl[r1];
    float M = fmaxf(m0, m1);
    float w0 = l0 * exp2f(m0 - M), w1 = l1 * exp2f(m1 - M);
    float inv = 1.f / (w0 + w1);
    w0 *= inv; w1 *= inv;
    bf16x8 a0 = *(const bf16x8*)(pacc + r0 * CQ + cg);
    bf16x8 a1 = *(const bf16x8*)(pacc + r1 * CQ + cg);
    bf16x8 o;
#pragma unroll
    for (int j = 0; j < 8; j++)
        o[j] = (short)f2bf(bf2f((u16)a0[j]) * w0 + bf2f((u16)a1[j]) * w1);
    *(bf16x8*)(aT + ((size_t)b * TT + t) * CQ + cg) = o;
}

extern "C" void kernel_launch(void* const* d_in, const int* in_sizes, int n_in,
                              void* d_out, int out_size, void* d_ws, size_t ws_size,
                              hipStream_t stream) {
    const float* key_feat = (const float*)d_in[0];
    const float* query    = (const float*)d_in[1];
    const float* WM       = (const float*)d_in[2];
    const float* kpw      = (const float*)d_in[3];
    const float* norm_w   = (const float*)d_in[4];
    const float* norm_b   = (const float*)d_in[5];
    const float* qkv_w    = (const float*)d_in[6];
    const float* qkv_b    = (const float*)d_in[7];
    const float* proj_w   = (const float*)d_in[8];
    const float* proj_b   = (const float*)d_in[9];
    float* out = (float*)d_out;
    char* ws = (char*)d_ws;

    u16* kdsT = (u16*)(ws);                 // [0, 8.4M)   dead after kraw gemm
    u16* kraw = (u16*)(ws + 8388608);       // [8.4, 25.2M) dead after affine#2
    u16* qnT  = (u16*)(ws + 25165824);      // dead after qkv gemms
    u16* knT  = (u16*)(ws + 41943040);      // dead after qkv gemms
    u16* pacc = (u16*)(ws + 25165824);      // 33.5 MB over qnT+knT (dead by flash)
    u16* qqT  = (u16*)(ws + 58720256);
    u16* kkT  = (u16*)(ws + 75497472);
    u16* vvp  = (u16*)(ws + 92274688);
    u16* aT   = (u16*)(ws);                 // [0, 16.8M) over kdsT+kraw head (dead by combine)
    u16* wqkv = (u16*)(ws + 16777216);      // over kraw tail, written after affine#2
    u16* wproj= (u16*)(ws + 19922944);      // ends at 20447232
    float* pm = (float*)(ws + 20447232);    // 128KB, in dead kraw tail gap
    float* pl = (float*)(ws + 20578304);    // 128KB, ends 20709376 < 25165824
    float* qsc = (float*)(ws + 109051904);
    float* qsh = qsc + NB * CQ;
    float* ksc = qsh + NB * CQ;
    float* ksh = ksc + NB * CQ;
    u16* wkp  = (u16*)(ws + 109084672);     // 256KB

    // 0. convert key_proj_w to bf16
    wconv_kernel<<<64, 256, 0, stream>>>(kpw, wkp, 512 * 256, 0, 0);
    // 1. pool + transpose
    pool_tr_kernel<<<dim3(64, NB), 256, 0, stream>>>(key_feat, kdsT);
    // 2. k_raw = key_proj_w @ kds   (staged GEMM)
    gemm_st_kernel<0, 0, 0><<<dim3(4, 32, NB), 256, 0, stream>>>(
        wkp, kdsT, nullptr, CK, nullptr, kraw, nullptr, nullptr, nullptr, nullptr, nullptr);
    // 3. group-norm stats
    gn_stats_kernel<0><<<dim3(32, NB), 256, 0, stream>>>(query, norm_w, norm_b, qsc, qsh);
    gn_stats_kernel<1><<<dim3(32, NB), 256, 0, stream>>>(kraw, norm_w, norm_b, ksc, ksh);
    // 4. normalized, transposed activations
    affine_tr_kernel<0><<<dim3(64, 8, NB), 256, 0, stream>>>(query, qsc, qsh, qnT);
    affine_tr_kernel<1><<<dim3(64, 8, NB), 256, 0, stream>>>(kraw, ksc, ksh, knT);
    // 4b. convert qkv_w (q rows *SQ*log2e, k rows *SQ) + proj_w to bf16
    wconv_kernel<<<768, 256, 0, stream>>>(qkv_w, wqkv, 1536 * 1024, 512 * 1024, 1024 * 1024);
    wconv_kernel<<<128, 256, 0, stream>>>(proj_w, wproj, 512 * 512, 0, 0);
    // 5. qkv projection: qq/kk swapped+transposed store, vv natural
    gemm_st_kernel<1, 1, 1><<<dim3(8, 32, NB), 256, 0, stream>>>(
        wqkv, qnT, knT, 1024, qkv_b, qqT, kkT, nullptr, nullptr, nullptr, nullptr);
    gemm_st_kernel<1, 1, 0><<<dim3(4, 32, NB), 256, 0, stream>>>(
        wqkv + (size_t)1024 * 1024, qnT, knT, 1024, qkv_b + 1024, vvp, nullptr, nullptr,
        nullptr, nullptr, nullptr);
    // 6. flash attention (v11: 2 blocks/CU, register-dieted) + combine
    flash_kernel<<<dim3(64, NCH, NB), 512, 0, stream>>>(qqT, kkT, vvp, WM, pacc, pm, pl);
    combine_kernel<<<dim3(TT / 4, NB), 256, 0, stream>>>(pacc, pm, pl, aT);
    // 7. out = GN(query) + proj_w @ a + proj_b
    gemm_st_kernel<2, 0, 0><<<dim3(4, 32, NB), 256, 0, stream>>>(
        wproj, aT, nullptr, CQ, proj_b, nullptr, nullptr, out, query, qsc, qsh);
}

// Round 12
// 542.020 us; speedup vs baseline: 2.1251x; 2.1251x over previous
//
#include <hip/hip_runtime.h>
#include <hip/hip_bf16.h>
#include <stdint.h>

#define NB 4
#define CQ 512
#define CK 256
#define TT 4096
#define SCALE_QK 0.21022410381342863f  // 512^-0.25

using bf16x8 = __attribute__((ext_vector_type(8))) short;
using short4v = __attribute__((ext_vector_type(4))) short;
using f32x4  = __attribute__((ext_vector_type(4))) float;
using u32x4  = __attribute__((ext_vector_type(4))) unsigned int;
typedef unsigned short u16;

__device__ __forceinline__ u16 f2bf(float f) {
    union { float f; unsigned u; } v; v.f = f;
    return (u16)((v.u + 0x7fffu + ((v.u >> 16) & 1u)) >> 16);
}
__device__ __forceinline__ float bf2f(u16 h) {
    union { float f; unsigned u; } v; v.u = ((unsigned)h) << 16;
    return v.f;
}
__device__ __forceinline__ bf16x8 pack8(f32x4 a, f32x4 b) {
    bf16x8 r;
    r[0] = (short)f2bf(a[0]); r[1] = (short)f2bf(a[1]);
    r[2] = (short)f2bf(a[2]); r[3] = (short)f2bf(a[3]);
    r[4] = (short)f2bf(b[0]); r[5] = (short)f2bf(b[1]);
    r[6] = (short)f2bf(b[2]); r[7] = (short)f2bf(b[3]);
    return r;
}
// async global->LDS, 16B per lane; LDS dest = wave-uniform base + lane*16
__device__ __forceinline__ void gload_lds16(const void* g, void* l) {
    __builtin_amdgcn_global_load_lds(
        (const __attribute__((address_space(1))) unsigned int*)g,
        (__attribute__((address_space(3))) unsigned int*)l, 16, 0, 0);
}

// ---- weight f32 -> bf16 conversion (optionally scale first scale_until elements) ----
__global__ __launch_bounds__(256) void wconv_kernel(const float* __restrict__ src,
        u16* __restrict__ dst, int n, int scale_until) {
    int i = (blockIdx.x * 256 + threadIdx.x) * 8;
    if (i >= n) return;
    f32x4 a = *(const f32x4*)(src + i);
    f32x4 c = *(const f32x4*)(src + i + 4);
    if (i < scale_until) {
        a *= SCALE_QK;
        c *= SCALE_QK;
    }
    *(bf16x8*)(dst + i) = pack8(a, c);
}

// ---- 2x2 avg pool of key_feat (b,256,128,128) -> kdsT (b,4096,256) bf16 ----
// vectorized: each thread produces 2 adjacent outputs from 2 float4 row loads
__global__ __launch_bounds__(256) void pool_tr_kernel(const float* __restrict__ kf,
                                                      u16* __restrict__ kdsT) {
    int h = blockIdx.x, b = blockIdx.y;
    __shared__ u16 tile[64][264];  // [w][c], padded
    for (int idx = threadIdx.x; idx < 32 * 256; idx += 256) {
        int wp = idx & 31, c = idx >> 5;  // wp = output-w pair index
        const float* base = kf + (((size_t)b * CK + c) * 128 + 2 * h) * 128 + 4 * wp;
        f32x4 r0 = *(const f32x4*)base;
        f32x4 r1 = *(const f32x4*)(base + 128);
        tile[2 * wp][c]     = f2bf(0.25f * (r0[0] + r0[1] + r1[0] + r1[1]));
        tile[2 * wp + 1][c] = f2bf(0.25f * (r0[2] + r0[3] + r1[2] + r1[3]));
    }
    __syncthreads();
    for (int idx = threadIdx.x; idx < 64 * 32; idx += 256) {
        int w = idx >> 5, cg = (idx & 31) << 3;
        *(u32x4*)(kdsT + ((size_t)b * TT + h * 64 + w) * CK + cg) = *(const u32x4*)&tile[w][cg];
    }
}

// ---- GroupNorm stats -> per-channel scale/shift (folded affine) ----
template <int ISBF>
__global__ __launch_bounds__(256) void gn_stats_kernel(const void* __restrict__ xv,
        const float* __restrict__ gw, const float* __restrict__ gb,
        float* __restrict__ sc, float* __restrict__ sh) {
    int g = blockIdx.x, b = blockIdx.y;
    size_t base = ((size_t)b * CQ + g * 16) * TT;
    float s = 0.f, q = 0.f;
    for (int i = threadIdx.x * 4; i < 16 * TT; i += 256 * 4) {
        float v0, v1, v2, v3;
        if constexpr (ISBF) {
            const u16* x = (const u16*)xv;
            uint2 u = *(const uint2*)(x + base + i);
            v0 = bf2f((u16)(u.x & 0xffff)); v1 = bf2f((u16)(u.x >> 16));
            v2 = bf2f((u16)(u.y & 0xffff)); v3 = bf2f((u16)(u.y >> 16));
        } else {
            const float* x = (const float*)xv;
            f32x4 v = *(const f32x4*)(x + base + i);
            v0 = v[0]; v1 = v[1]; v2 = v[2]; v3 = v[3];
        }
        s += v0 + v1 + v2 + v3;
        q += v0 * v0 + v1 * v1 + v2 * v2 + v3 * v3;
    }
#pragma unroll
    for (int d = 1; d < 64; d <<= 1) { s += __shfl_xor(s, d, 64); q += __shfl_xor(q, d, 64); }
    __shared__ float shs[4], shq[4];
    int wid = threadIdx.x >> 6;
    if ((threadIdx.x & 63) == 0) { shs[wid] = s; shq[wid] = q; }
    __syncthreads();
    if (threadIdx.x < 16) {
        float S = shs[0] + shs[1] + shs[2] + shs[3];
        float Q = shq[0] + shq[1] + shq[2] + shq[3];
        const float inv = 1.f / (16.f * TT);
        float mean = S * inv, var = Q * inv - mean * mean;
        float rstd = rsqrtf(var + 1e-5f);
        int c = g * 16 + threadIdx.x;
        float w = gw[c] * rstd;
        sc[b * CQ + c] = w;
        sh[b * CQ + c] = gb[c] - mean * w;
    }
}

// ---- affine + transpose: in (b,512,T) -> out (b,T,512) bf16 ----
// vectorized: each thread handles 4 consecutive t (float4 / short4 loads)
template <int ISBF>
__global__ __launch_bounds__(256) void affine_tr_kernel(const void* __restrict__ xv,
        const float* __restrict__ sc, const float* __restrict__ sh, u16* __restrict__ out) {
    int t0 = blockIdx.x * 64, c0 = blockIdx.y * 64, b = blockIdx.z;
    __shared__ u16 tile[64][72];  // [t][c]
    for (int idx = threadIdx.x; idx < 16 * 64; idx += 256) {
        int tq = idx & 15, cl = idx >> 4;
        int c = c0 + cl;
        float w = sc[b * CQ + c], z = sh[b * CQ + c];
        float v[4];
        if constexpr (ISBF) {
            short4v u = *(const short4v*)((const u16*)xv + ((size_t)b * CQ + c) * TT + t0 + 4 * tq);
#pragma unroll
            for (int j = 0; j < 4; j++) v[j] = bf2f((u16)u[j]);
        } else {
            f32x4 u = *(const f32x4*)((const float*)xv + ((size_t)b * CQ + c) * TT + t0 + 4 * tq);
#pragma unroll
            for (int j = 0; j < 4; j++) v[j] = u[j];
        }
#pragma unroll
        for (int j = 0; j < 4; j++) tile[4 * tq + j][cl] = f2bf(v[j] * w + z);
    }
    __syncthreads();
    for (int idx = threadIdx.x; idx < 64 * 8; idx += 256) {
        int tl = idx >> 3, cg = (idx & 7) << 3;
        *(u32x4*)(out + ((size_t)b * TT + t0 + tl) * CQ + c0 + cg) = *(const u32x4*)&tile[tl][cg];
    }
}

// ---- staged GEMM: 128o x 128t tile, BK=64, double-buffered LDS, global_load_lds ----
template <int EPI, int CONCAT, int SWAP>
__global__ __launch_bounds__(256) void gemm_st_kernel(
        const u16* __restrict__ Wb, const u16* __restrict__ X1, const u16* __restrict__ X2,
        int Ktot, const float* __restrict__ bias,
        u16* __restrict__ outb, u16* __restrict__ outb2, float* __restrict__ outf,
        const float* __restrict__ query, const float* __restrict__ qsc,
        const float* __restrict__ qsh) {
    int b = blockIdx.z;
    int o0 = blockIdx.x * 128, t0 = blockIdx.y * 128;
    int wid = threadIdx.x >> 6, lane = threadIdx.x & 63;
    int lr = lane & 15, lg = lane >> 4;
    int osub = (wid >> 1) * 64, tsub = (wid & 1) * 64;

    __shared__ u16 Wl[2][128][64];
    __shared__ u16 Xl[2][128][64];

    const int Kx = CONCAT ? 512 : Ktot;
    int srow = lane >> 3;
    int sxw = ((lane & 7) ^ srow) << 4;
    int xr = (lr & 7) << 4;

    f32x4 acc[4][4];
#pragma unroll
    for (int i = 0; i < 4; i++)
#pragma unroll
        for (int j = 0; j < 4; j++) acc[i][j] = f32x4{0.f, 0.f, 0.f, 0.f};

    int nk = Ktot >> 6;

#define STAGE_TILE(KC, BUF)                                                          \
    do {                                                                             \
        int c0_ = (KC) << 6;                                                         \
        const u16* xs_;                                                              \
        if (CONCAT && c0_ >= 512) xs_ = X2 + ((size_t)b * TT) * 512 + (c0_ - 512);   \
        else if (CONCAT)          xs_ = X1 + ((size_t)b * TT) * 512 + c0_;           \
        else                      xs_ = X1 + ((size_t)b * TT) * (size_t)Ktot + c0_;  \
        const char* xb_ = (const char*)(xs_ + (size_t)(t0 + wid * 32) * Kx) + sxw;   \
        const char* wb_ = (const char*)(Wb + (size_t)(o0 + wid * 32) * Ktot + c0_) + sxw; \
        _Pragma("unroll")                                                            \
        for (int i_ = 0; i_ < 4; i_++) {                                             \
            gload_lds16(xb_ + (size_t)(i_ * 8 + srow) * (Kx * 2),                    \
                        &Xl[BUF][wid * 32 + i_ * 8][0]);                             \
            gload_lds16(wb_ + (size_t)(i_ * 8 + srow) * (Ktot * 2),                  \
                        &Wl[BUF][wid * 32 + i_ * 8][0]);                             \
        }                                                                            \
    } while (0)

    STAGE_TILE(0, 0);
    __syncthreads();
    int cur = 0;
    for (int kc = 0; kc < nk; kc++) {
        if (kc + 1 < nk) STAGE_TILE(kc + 1, cur ^ 1);
#pragma unroll
        for (int kk = 0; kk < 2; kk++) {
            int boff = (kk * 64 + lg * 16) ^ xr;
            bf16x8 am[4], bn[4];
#pragma unroll
            for (int mi = 0; mi < 4; mi++) {
                if (SWAP) am[mi] = *(const bf16x8*)((const char*)&Xl[cur][tsub + mi * 16 + lr][0] + boff);
                else      am[mi] = *(const bf16x8*)((const char*)&Wl[cur][osub + mi * 16 + lr][0] + boff);
            }
#pragma unroll
            for (int ni = 0; ni < 4; ni++) {
                if (SWAP) bn[ni] = *(const bf16x8*)((const char*)&Wl[cur][osub + ni * 16 + lr][0] + boff);
                else      bn[ni] = *(const bf16x8*)((const char*)&Xl[cur][tsub + ni * 16 + lr][0] + boff);
            }
#pragma unroll
            for (int mi = 0; mi < 4; mi++)
#pragma unroll
                for (int ni = 0; ni < 4; ni++)
                    acc[mi][ni] = __builtin_amdgcn_mfma_f32_16x16x32_bf16(am[mi], bn[ni], acc[mi][ni], 0, 0, 0);
        }
        __syncthreads();
        cur ^= 1;
    }
#undef STAGE_TILE

    if (SWAP) {
#pragma unroll
        for (int mi = 0; mi < 4; mi++)
#pragma unroll
            for (int ni = 0; ni < 4; ni++)
#pragma unroll
                for (int reg = 0; reg < 4; reg++) {
                    int t = t0 + tsub + mi * 16 + 4 * lg + reg;
                    int o = o0 + osub + ni * 16 + lr;
                    float v = acc[mi][ni][reg] + bias[o] * SCALE_QK;
                    if (o < 512) outb[((size_t)b * TT + t) * 512 + o] = f2bf(v);
                    else         outb2[((size_t)b * TT + t) * 512 + (o - 512)] = f2bf(v);
                }
    } else {
#pragma unroll
        for (int mi = 0; mi < 4; mi++)
#pragma unroll
            for (int reg = 0; reg < 4; reg++) {
                int o = o0 + osub + mi * 16 + 4 * lg + reg;
                float bv = (EPI >= 1) ? bias[o] : 0.f;
#pragma unroll
                for (int ni = 0; ni < 4; ni++) {
                    int t = t0 + tsub + ni * 16 + lr;
                    size_t oidx = ((size_t)b * CQ + o) * TT + t;
                    float v = acc[mi][ni][reg] + bv;
                    if (EPI == 2) {
                        outf[oidx] = v + query[oidx] * qsc[b * CQ + o] + qsh[b * CQ + o];
                    } else {
                        outb[oidx] = f2bf(v);
                    }
                }
            }
    }
}

// ---- flash attention v4 (best measured: 380 us): LDS-staged K/V, 8 waves, 1 block/CU ----
// Block: 64 t-rows, full s sweep. Wave (tb,sb): QK 16t x 32s; PV 16t x 256c.
__global__ __launch_bounds__(512, 2) void flash_kernel(
        const u16* __restrict__ qqT, const u16* __restrict__ kkT,
        const u16* __restrict__ vv, const float* __restrict__ WM,
        u16* __restrict__ aT) {
    int b = blockIdx.y;
    int T0 = blockIdx.x * 64;
    int wid = threadIdx.x >> 6, lane = threadIdx.x & 63;
    int lr = lane & 15, lg = lane >> 4;
    int tb = wid >> 1, sb = wid & 1;

    __shared__ u16 K_lds[64][512];   // [s][c], chunk-swizzled by (s&7)
    __shared__ u16 V_lds[512][64];   // [c][s], chunk-swizzled by (c&7)
    __shared__ u16 p_lds[64][64];    // [t][s], chunk-swizzled by (t&7)
    __shared__ float ex_max[64][2];
    __shared__ float ex_sum[64][2];

    bf16x8 qf[16];
    {
        const u16* qrow = qqT + ((size_t)b * TT + T0 + 16 * tb + lr) * CQ + lg * 8;
#pragma unroll
        for (int kc = 0; kc < 16; kc++) qf[kc] = *(const bf16x8*)(qrow + kc * 32);
    }
    f32x4 acc[16];
#pragma unroll
    for (int i = 0; i < 16; i++) acc[i] = f32x4{0.f, 0.f, 0.f, 0.f};
    float m[4], l[4];
#pragma unroll
    for (int r = 0; r < 4; r++) { m[r] = -1e30f; l[r] = 0.f; }

    const float* wmrow = WM + ((size_t)b * TT + T0 + 16 * tb + 4 * lg) * TT + 32 * sb + lr;
    const char* kbase = (const char*)(kkT + ((size_t)b * TT) * CQ);
    int myt = 16 * tb + 4 * lg;

    for (int s0 = 0; s0 < TT; s0 += 64) {
        __syncthreads();  // bar1
#pragma unroll
        for (int i = 0; i < 8; i++) {
            int s = wid * 8 + i;
            gload_lds16(kbase + ((size_t)(s0 + s)) * 1024 + ((lane ^ (s & 7)) << 4),
                        &K_lds[s][0]);
        }
#pragma unroll
        for (int g2 = 0; g2 < 8; g2++) {
            int c0 = (wid * 8 + g2) * 8;
            int c = c0 + (lane >> 3);
            gload_lds16((const char*)(vv + ((size_t)b * CQ + c) * TT + s0) +
                            ((((lane & 7) ^ (c & 7))) << 4),
                        &V_lds[c0][0]);
        }
        float wmv[2][4];
#pragma unroll
        for (int fs = 0; fs < 2; fs++)
#pragma unroll
            for (int reg = 0; reg < 4; reg++)
                wmv[fs][reg] = wmrow[(size_t)reg * TT + s0 + fs * 16];
        __syncthreads();  // bar2

        f32x4 sacc[2];
        sacc[0] = f32x4{0.f, 0.f, 0.f, 0.f};
        sacc[1] = f32x4{0.f, 0.f, 0.f, 0.f};
#pragma unroll
        for (int kc = 0; kc < 16; kc++) {
#pragma unroll
            for (int fs = 0; fs < 2; fs++) {
                const char* kp = (const char*)&K_lds[32 * sb + fs * 16 + lr][0];
                bf16x8 kfr = *(const bf16x8*)(kp + ((((kc << 2) | lg) ^ (lr & 7)) << 4));
                sacc[fs] = __builtin_amdgcn_mfma_f32_16x16x32_bf16(qf[kc], kfr, sacc[fs], 0, 0, 0);
            }
        }
        float lgt[2][4], pmax[4];
#pragma unroll
        for (int r = 0; r < 4; r++) pmax[r] = -3e38f;
#pragma unroll
        for (int fs = 0; fs < 2; fs++)
#pragma unroll
            for (int reg = 0; reg < 4; reg++) {
                float v = sacc[fs][reg] * wmv[fs][reg];
                lgt[fs][reg] = v;
                pmax[reg] = fmaxf(pmax[reg], v);
            }
#pragma unroll
        for (int d = 1; d < 16; d <<= 1)
#pragma unroll
            for (int reg = 0; reg < 4; reg++)
                pmax[reg] = fmaxf(pmax[reg], __shfl_xor(pmax[reg], d, 64));
        if (lr == 0) {
#pragma unroll
            for (int reg = 0; reg < 4; reg++) ex_max[myt + reg][sb] = pmax[reg];
        }
        __syncthreads();  // bar3
        float fac[4], rsum[4];
#pragma unroll
        for (int reg = 0; reg < 4; reg++) {
            int t = myt + reg;
            float mn = fmaxf(m[reg], fmaxf(ex_max[t][0], ex_max[t][1]));
            fac[reg] = __expf(m[reg] - mn);
            m[reg] = mn;
            rsum[reg] = 0.f;
        }
#pragma unroll
        for (int fs = 0; fs < 2; fs++)
#pragma unroll
            for (int reg = 0; reg < 4; reg++) {
                float p = __expf(lgt[fs][reg] - m[reg]);
                rsum[reg] += p;
                int t = myt + reg;
                int s = 32 * sb + fs * 16 + lr;
                *(u16*)((char*)p_lds + t * 128 + ((((s >> 3) ^ (t & 7))) << 4) + ((s & 7) << 1)) = f2bf(p);
            }
#pragma unroll
        for (int d = 1; d < 16; d <<= 1)
#pragma unroll
            for (int reg = 0; reg < 4; reg++)
                rsum[reg] += __shfl_xor(rsum[reg], d, 64);
        if (lr == 0) {
#pragma unroll
            for (int reg = 0; reg < 4; reg++) ex_sum[myt + reg][sb] = rsum[reg];
        }
        __syncthreads();  // bar4
#pragma unroll
        for (int reg = 0; reg < 4; reg++) {
            int t = myt + reg;
            l[reg] = l[reg] * fac[reg] + ex_sum[t][0] + ex_sum[t][1];
        }
#pragma unroll
        for (int nt = 0; nt < 16; nt++)
#pragma unroll
            for (int reg = 0; reg < 4; reg++) acc[nt][reg] *= fac[reg];
#pragma unroll
        for (int ks = 0; ks < 2; ks++) {
            int prow = 16 * tb + lr;
            bf16x8 pa = *(const bf16x8*)((const char*)p_lds + prow * 128 +
                                         ((((ks << 2) | lg) ^ (lr & 7)) << 4));
#pragma unroll
            for (int nt = 0; nt < 16; nt++) {
                int vr = 256 * sb + nt * 16 + lr;
                bf16x8 vf = *(const bf16x8*)((const char*)&V_lds[vr][0] +
                                             ((((ks << 2) | lg) ^ (lr & 7)) << 4));
                acc[nt] = __builtin_amdgcn_mfma_f32_16x16x32_bf16(pa, vf, acc[nt], 0, 0, 0);
            }
        }
    }
    float inv[4];
#pragma unroll
    for (int reg = 0; reg < 4; reg++) inv[reg] = 1.f / l[reg];
#pragma unroll
    for (int nt = 0; nt < 16; nt++)
#pragma unroll
        for (int reg = 0; reg < 4; reg++) {
            int t = T0 + myt + reg;
            int c = 256 * sb + nt * 16 + lr;
            aT[((size_t)b * TT + t) * CQ + c] = f2bf(acc[nt][reg] * inv[reg]);
        }
}

extern "C" void kernel_launch(void* const* d_in, const int* in_sizes, int n_in,
                              void* d_out, int out_size, void* d_ws, size_t ws_size,
                              hipStream_t stream) {
    const float* key_feat = (const float*)d_in[0];
    const float* query    = (const float*)d_in[1];
    const float* WM       = (const float*)d_in[2];
    const float* kpw      = (const float*)d_in[3];
    const float* norm_w   = (const float*)d_in[4];
    const float* norm_b   = (const float*)d_in[5];
    const float* qkv_w    = (const float*)d_in[6];
    const float* qkv_b    = (const float*)d_in[7];
    const float* proj_w   = (const float*)d_in[8];
    const float* proj_b   = (const float*)d_in[9];
    float* out = (float*)d_out;
    char* ws = (char*)d_ws;

    u16* kdsT = (u16*)(ws);                 // [0, 8.4M)   dead after kraw gemm
    u16* kraw = (u16*)(ws + 8388608);       // [8.4, 25.2M) dead after affine#2
    u16* qnT  = (u16*)(ws + 25165824);      // dead after qkv gemms
    u16* knT  = (u16*)(ws + 41943040);      // dead after qkv gemms
    u16* qqT  = (u16*)(ws + 58720256);
    u16* kkT  = (u16*)(ws + 75497472);
    u16* vvp  = (u16*)(ws + 92274688);
    u16* aT   = (u16*)(ws);                 // [0, 16.8M) over kdsT+kraw head (dead by flash)
    u16* wqkv = (u16*)(ws + 16777216);      // over kraw tail, written after affine#2
    u16* wproj= (u16*)(ws + 19922944);
    float* qsc = (float*)(ws + 109051904);
    float* qsh = qsc + NB * CQ;
    float* ksc = qsh + NB * CQ;
    float* ksh = ksc + NB * CQ;
    u16* wkp  = (u16*)(ws + 109084672);     // 256KB

    // 0. convert key_proj_w to bf16
    wconv_kernel<<<64, 256, 0, stream>>>(kpw, wkp, 512 * 256, 0);
    // 1. pool + transpose
    pool_tr_kernel<<<dim3(64, NB), 256, 0, stream>>>(key_feat, kdsT);
    // 2. k_raw = key_proj_w @ kds   (staged GEMM)
    gemm_st_kernel<0, 0, 0><<<dim3(4, 32, NB), 256, 0, stream>>>(
        wkp, kdsT, nullptr, CK, nullptr, kraw, nullptr, nullptr, nullptr, nullptr, nullptr);
    // 3. group-norm stats
    gn_stats_kernel<0><<<dim3(32, NB), 256, 0, stream>>>(query, norm_w, norm_b, qsc, qsh);
    gn_stats_kernel<1><<<dim3(32, NB), 256, 0, stream>>>(kraw, norm_w, norm_b, ksc, ksh);
    // 4. normalized, transposed activations
    affine_tr_kernel<0><<<dim3(64, 8, NB), 256, 0, stream>>>(query, qsc, qsh, qnT);
    affine_tr_kernel<1><<<dim3(64, 8, NB), 256, 0, stream>>>(kraw, ksc, ksh, knT);
    // 4b. convert qkv_w (q/k rows pre-scaled) + proj_w to bf16 (kraw now dead)
    wconv_kernel<<<768, 256, 0, stream>>>(qkv_w, wqkv, 1536 * 1024, 1024 * 1024);
    wconv_kernel<<<128, 256, 0, stream>>>(proj_w, wproj, 512 * 512, 0);
    // 5. qkv projection: qq/kk swapped+transposed store, vv natural
    gemm_st_kernel<1, 1, 1><<<dim3(8, 32, NB), 256, 0, stream>>>(
        wqkv, qnT, knT, 1024, qkv_b, qqT, kkT, nullptr, nullptr, nullptr, nullptr);
    gemm_st_kernel<1, 1, 0><<<dim3(4, 32, NB), 256, 0, stream>>>(
        wqkv + (size_t)1024 * 1024, qnT, knT, 1024, qkv_b + 1024, vvp, nullptr, nullptr,
        nullptr, nullptr, nullptr);
    // 6. flash attention (v4, best measured)
    flash_kernel<<<dim3(64, NB), 512, 0, stream>>>(qqT, kkT, vvp, WM, aT);
    // 7. out = GN(query) + proj_w @ a + proj_b
    gemm_st_kernel<2, 0, 0><<<dim3(4, 32, NB), 256, 0, stream>>>(
        wproj, aT, nullptr, CQ, proj_b, nullptr, nullptr, out, query, qsc, qsh);
}